// Round 4
// baseline (688.751 us; speedup 1.0000x reference)
//
#include <hip/hip_runtime.h>

// EdgeNorm, round 8: payload counting-sort -> streaming stats, ws-floor-safe.
//
// Rounds 6/7 died identically with and without OOB guards -> kernel-bug
// theory weakened. New theory: those builds needed >=61MB of workspace;
// all we KNOW (from round 4/5 passing) is ws_size >= 50.6MB. In the gap,
// the never-tested 54M-global-atomic fallback ran -> plausible timeout ->
// container death. This round shrinks the sorted path to ~47.7MB (P=4,
// PARTS_B=2, CBLK=512) so it fits under the PROVEN floor and the fallback
// is unreachable on this machine.
//
// Round-5 lesson (rocprof) still drives the design: stats' random 64B
// gather of scores[e] is a ~680 GB/s pattern wall (302us). The counting
// sort gives each (bucket,block) a contiguous output range, so scatter
// locally orders its chunk by bucket in LDS and emits the 32B score
// payload in contiguous runs; stats then streams coalesced.
//
// Pipeline per pass (P in {2,4,8}, smallest that fits ws):
//   1. count   : LDS histogram of dst>>9 per chunk -> counts[b][blk]
//   2. scan    : per-bucket exclusive prefix over blocks (+ totals[b])
//   3. base    : exclusive prefix over bucket totals -> base[b] (compact)
//   4. scatter : LDS-order chunk by bucket; payload[g]=scores[e] (8 f32),
//                nidx[g]=node&511 (u16); ~256-512B contiguous runs
//   5. stats   : block (part,bucket) STREAMS its payload run, accumulates
//                512x17 LDS tile, writes/adds partials
// then:
//   6. coeff   : reduce partials; AB[node] = [A(8)|B(8)] one 64B line
//   7. edge_out: out = A[dst]*x + B[dst]

#define NHEADS  8
#define KSHIFT  9
#define KNODES  512
#define SLOTS   17            // 8 sum + 8 sumsq + 1 count
#define NNODES  100000
#define NB      196           // ceil(100000/512)
#define CBLK    512           // count/scatter blocks
#define CHMAX   3200          // max chunk (local edge idx fits 12 bits)
#define PARTS_B 2

__global__ __launch_bounds__(256)
void count_kernel(const int* __restrict__ dst, unsigned* __restrict__ counts,
                  int p0, int p1, int chunk) {
    __shared__ unsigned hist[NB];
    for (int i = threadIdx.x; i < NB; i += 256) hist[i] = 0u;
    __syncthreads();
    const int blk = blockIdx.x;
    const int s0 = p0 + blk * chunk;
    const int s1 = min(s0 + chunk, p1);
    for (int i = s0 + (int)threadIdx.x * 4; i < s1; i += 256 * 4) {
        if (i + 4 <= s1) {
            int4 d = *reinterpret_cast<const int4*>(dst + i);
            atomicAdd(&hist[(unsigned)d.x >> KSHIFT], 1u);
            atomicAdd(&hist[(unsigned)d.y >> KSHIFT], 1u);
            atomicAdd(&hist[(unsigned)d.z >> KSHIFT], 1u);
            atomicAdd(&hist[(unsigned)d.w >> KSHIFT], 1u);
        } else {
            for (int j = i; j < s1; ++j)
                atomicAdd(&hist[(unsigned)dst[j] >> KSHIFT], 1u);
        }
    }
    __syncthreads();
    for (int b = threadIdx.x; b < NB; b += 256)
        counts[(size_t)b * CBLK + blk] = hist[b];
}

// One block per bucket: exclusive scan of counts[b][0..CBLK) in place.
// CBLK=512 -> uint2 per thread (256 threads x 2 = 512).
__global__ __launch_bounds__(256)
void scan_kernel(unsigned* __restrict__ counts, unsigned* __restrict__ totals) {
    __shared__ unsigned sc[256];
    const int b = blockIdx.x;
    const size_t base = (size_t)b * CBLK + (size_t)threadIdx.x * 2;
    uint2 v = *reinterpret_cast<uint2*>(counts + base);
    unsigned s = v.x + v.y;
    sc[threadIdx.x] = s;
    __syncthreads();
    for (int off = 1; off < 256; off <<= 1) {
        unsigned t = (threadIdx.x >= (unsigned)off) ? sc[threadIdx.x - off] : 0u;
        __syncthreads();
        sc[threadIdx.x] += t;
        __syncthreads();
    }
    unsigned excl = sc[threadIdx.x] - s;
    uint2 o;
    o.x = excl;
    o.y = excl + v.x;
    *reinterpret_cast<uint2*>(counts + base) = o;
    if (threadIdx.x == 255) totals[b] = sc[255];
}

// Single block: exclusive prefix over bucket totals -> compact bucket bases.
__global__ __launch_bounds__(256)
void base_kernel(const unsigned* __restrict__ totals, unsigned* __restrict__ base) {
    __shared__ unsigned sc[256];
    unsigned v = (threadIdx.x < NB) ? totals[threadIdx.x] : 0u;
    sc[threadIdx.x] = v;
    __syncthreads();
    for (int off = 1; off < 256; off <<= 1) {
        unsigned t = (threadIdx.x >= (unsigned)off) ? sc[threadIdx.x - off] : 0u;
        __syncthreads();
        sc[threadIdx.x] += t;
        __syncthreads();
    }
    if (threadIdx.x < NB) base[threadIdx.x] = sc[threadIdx.x] - v;
}

// Local counting sort of the chunk by bucket, then coalesced payload emit.
// ord[] entry: local edge idx (12b) | node-in-bucket (9b, <<12) | bucket (<<21)
__global__ __launch_bounds__(256)
void scatter_kernel(const int* __restrict__ dst,
                    const unsigned* __restrict__ counts,
                    const unsigned* __restrict__ base,
                    const float* __restrict__ scores,
                    float* __restrict__ payload,
                    unsigned short* __restrict__ nidx,
                    int p0, int p1, int chunk, unsigned capE) {
    __shared__ unsigned hist[256];      // padded to 256 for the scan
    __shared__ unsigned pfx[NB];        // local exclusive prefix
    __shared__ unsigned lofs[NB];       // running local offsets
    __shared__ unsigned gbase[NB];      // global dest base for this block's run
    __shared__ unsigned ord[CHMAX];
    const int blk = blockIdx.x;
    const int s0 = p0 + blk * chunk;
    const int s1 = min(s0 + chunk, p1);
    const int n  = s1 - s0;

    hist[threadIdx.x] = 0u;
    __syncthreads();
    // phase 1: local histogram
    for (int i = s0 + (int)threadIdx.x * 4; i < s1; i += 256 * 4) {
        if (i + 4 <= s1) {
            int4 d = *reinterpret_cast<const int4*>(dst + i);
            atomicAdd(&hist[(unsigned)d.x >> KSHIFT], 1u);
            atomicAdd(&hist[(unsigned)d.y >> KSHIFT], 1u);
            atomicAdd(&hist[(unsigned)d.z >> KSHIFT], 1u);
            atomicAdd(&hist[(unsigned)d.w >> KSHIFT], 1u);
        } else {
            for (int j = i; j < s1; ++j)
                atomicAdd(&hist[(unsigned)dst[j] >> KSHIFT], 1u);
        }
    }
    __syncthreads();
    // phase 2: in-place inclusive scan of hist -> exclusive pfx
    unsigned myc = hist[threadIdx.x];
    for (int off = 1; off < 256; off <<= 1) {
        unsigned t = (threadIdx.x >= (unsigned)off) ? hist[threadIdx.x - off] : 0u;
        __syncthreads();
        hist[threadIdx.x] += t;
        __syncthreads();
    }
    unsigned excl = hist[threadIdx.x] - myc;
    if (threadIdx.x < NB) {
        pfx[threadIdx.x]  = excl;
        lofs[threadIdx.x] = excl;
        gbase[threadIdx.x] =
            base[threadIdx.x] + counts[(size_t)threadIdx.x * CBLK + blk];
    }
    __syncthreads();
    // phase 3: bucket-order the chunk's edge ids in LDS
    for (int i = s0 + (int)threadIdx.x; i < s1; i += 256) {
        int d = dst[i];
        unsigned b = (unsigned)d >> KSHIFT;
        unsigned pos = atomicAdd(&lofs[b], 1u);
        if (pos < (unsigned)CHMAX)          // invariant: pos < n <= CHMAX
            ord[pos] = (unsigned)(i - s0) |
                       ((unsigned)(d & (KNODES - 1)) << 12) | (b << 21);
    }
    __syncthreads();
    // phase 4: emit payload in bucket order -> contiguous runs.
    // scores gather is a permutation within the chunk's window (L2-hot).
    for (int p = (int)threadIdx.x; p < n; p += 256) {
        unsigned r = ord[p];
        int el       = (int)(r & 0xFFFu);
        unsigned nib = (r >> 12) & 0x1FFu;
        unsigned b   = r >> 21;
        unsigned gi  = gbase[b] + (unsigned)p - pfx[b];
        if (gi >= capE) continue;           // invariant: gi < pass edge count
        const float4* ps = reinterpret_cast<const float4*>(
            scores + (size_t)(s0 + el) * NHEADS);
        float4 x0 = ps[0], x1 = ps[1];
        float4* pd = reinterpret_cast<float4*>(payload + (size_t)gi * NHEADS);
        pd[0] = x0;
        pd[1] = x1;
        nidx[gi] = (unsigned short)nib;
    }
}

__global__ __launch_bounds__(256)
void stats_kernel(const float* __restrict__ payload,
                  const unsigned short* __restrict__ nidx,
                  const unsigned* __restrict__ totals,
                  const unsigned* __restrict__ base,
                  float* __restrict__ partials, int add) {
    __shared__ float st[KNODES * SLOTS];     // 34816 B -> 4 blocks/CU
    const int part = blockIdx.x;
    const int b    = blockIdx.y;
    float4* stv = reinterpret_cast<float4*>(st);
    for (int i = threadIdx.x; i < (KNODES * SLOTS) / 4; i += 256)
        stv[i] = float4{0.f, 0.f, 0.f, 0.f};
    __syncthreads();

    const int cnt   = (int)totals[b];
    const int start = (int)base[b];
    const int seg = (cnt + PARTS_B - 1) / PARTS_B;
    const int i0 = part * seg;
    const int i1 = min(cnt, i0 + seg);

    // Fully streaming walk; two edges per iteration for load-level parallelism.
    for (int i = i0 + (int)threadIdx.x; i < i1; i += 512) {
        int j = i + 256;
        const float4* pv0 = reinterpret_cast<const float4*>(
            payload + (size_t)(start + i) * NHEADS);
        float4 a0 = pv0[0], c0 = pv0[1];
        unsigned n0 = nidx[start + i] & (KNODES - 1);
        float4 a1, c1;
        unsigned n1 = 0;
        bool has1 = (j < i1);
        if (has1) {
            const float4* pv1 = reinterpret_cast<const float4*>(
                payload + (size_t)(start + j) * NHEADS);
            a1 = pv1[0]; c1 = pv1[1];
            n1 = nidx[start + j] & (KNODES - 1);
        }
        {
            float* s = st + (int)n0 * SLOTS;   // stride 17: odd
            atomicAdd(s + 0,  a0.x);       atomicAdd(s + 1,  a0.y);
            atomicAdd(s + 2,  a0.z);       atomicAdd(s + 3,  a0.w);
            atomicAdd(s + 4,  c0.x);       atomicAdd(s + 5,  c0.y);
            atomicAdd(s + 6,  c0.z);       atomicAdd(s + 7,  c0.w);
            atomicAdd(s + 8,  a0.x * a0.x); atomicAdd(s + 9,  a0.y * a0.y);
            atomicAdd(s + 10, a0.z * a0.z); atomicAdd(s + 11, a0.w * a0.w);
            atomicAdd(s + 12, c0.x * c0.x); atomicAdd(s + 13, c0.y * c0.y);
            atomicAdd(s + 14, c0.z * c0.z); atomicAdd(s + 15, c0.w * c0.w);
            atomicAdd(s + 16, 1.0f);
        }
        if (has1) {
            float* s = st + (int)n1 * SLOTS;
            atomicAdd(s + 0,  a1.x);       atomicAdd(s + 1,  a1.y);
            atomicAdd(s + 2,  a1.z);       atomicAdd(s + 3,  a1.w);
            atomicAdd(s + 4,  c1.x);       atomicAdd(s + 5,  c1.y);
            atomicAdd(s + 6,  c1.z);       atomicAdd(s + 7,  c1.w);
            atomicAdd(s + 8,  a1.x * a1.x); atomicAdd(s + 9,  a1.y * a1.y);
            atomicAdd(s + 10, a1.z * a1.z); atomicAdd(s + 11, a1.w * a1.w);
            atomicAdd(s + 12, c1.x * c1.x); atomicAdd(s + 13, c1.y * c1.y);
            atomicAdd(s + 14, c1.z * c1.z); atomicAdd(s + 15, c1.w * c1.w);
            atomicAdd(s + 16, 1.0f);
        }
    }
    __syncthreads();

    float* out = partials + ((size_t)b * PARTS_B + part) * (KNODES * SLOTS);
    float4* outv = reinterpret_cast<float4*>(out);
    if (add) {
        for (int i = threadIdx.x; i < (KNODES * SLOTS) / 4; i += 256) {
            float4 o = outv[i], v = stv[i];
            o.x += v.x; o.y += v.y; o.z += v.z; o.w += v.w;
            outv[i] = o;
        }
    } else {
        for (int i = threadIdx.x; i < (KNODES * SLOTS) / 4; i += 256)
            outv[i] = stv[i];
    }
}

// AB layout: per node 16 floats = one 64B line: [A(8) | B(8)].
__global__ __launch_bounds__(256)
void coeff_kernel(const float* __restrict__ partials,
                  const float* __restrict__ gain,
                  const float* __restrict__ bias,
                  float* __restrict__ AB, int total) {
    int i = blockIdx.x * 256 + threadIdx.x;
    if (i >= total) return;
    int node = i >> 3, h = i & 7;
    int b = node >> KSHIFT;
    int k = node & (KNODES - 1);
    const float* base =
        partials + (size_t)b * PARTS_B * (KNODES * SLOTS) + (size_t)k * SLOTS;
    float s = 0.f, q = 0.f, c = 0.f;
    #pragma unroll
    for (int p = 0; p < PARTS_B; p++) {
        const float* pp = base + (size_t)p * (KNODES * SLOTS);
        s += pp[h];
        q += pp[8 + h];
        c += pp[16];
    }
    float cm   = fmaxf(c, 1.0f);                 // ref: sums / max(counts,1)
    float mean = s / cm;
    float var  = fmaxf(q - s * mean, 0.0f);      // one-pass variance, clamped
    float inv  = 1.0f / fmaxf(sqrtf(var / cm), 1e-5f);
    float a = gain[h] * inv;
    AB[(size_t)node * 16 + h]     = a;
    AB[(size_t)node * 16 + 8 + h] = fmaf(-a, mean, bias[h]);
}

__global__ __launch_bounds__(256)
void edge_out_kernel(const float* __restrict__ scores,
                     const int* __restrict__ dst,
                     const float* __restrict__ AB,
                     float* __restrict__ out,
                     int num_edges) {
    int e = blockIdx.x * 256 + threadIdx.x;
    if (e >= num_edges) return;
    int d = dst[e];
    const float4* px  = reinterpret_cast<const float4*>(scores + (size_t)e * NHEADS);
    const float4* pab = reinterpret_cast<const float4*>(AB + (size_t)d * 16);
    float4 x0 = px[0], x1 = px[1];
    float4 a0 = pab[0], a1 = pab[1];
    float4 b0 = pab[2], b1 = pab[3];
    float4 o0, o1;
    o0.x = fmaf(a0.x, x0.x, b0.x);
    o0.y = fmaf(a0.y, x0.y, b0.y);
    o0.z = fmaf(a0.z, x0.z, b0.z);
    o0.w = fmaf(a0.w, x0.w, b0.w);
    o1.x = fmaf(a1.x, x1.x, b1.x);
    o1.y = fmaf(a1.y, x1.y, b1.y);
    o1.z = fmaf(a1.z, x1.z, b1.z);
    o1.w = fmaf(a1.w, x1.w, b1.w);
    float4* po = reinterpret_cast<float4*>(out + (size_t)e * NHEADS);
    po[0] = o0;
    po[1] = o1;
}

// ---- global-atomic fallback (unreachable when ws >= ~35MB; kept as net) ---
__global__ void edge_stats_fallback(const float* __restrict__ scores,
                                    const int* __restrict__ dst,
                                    float* __restrict__ sums,
                                    float* __restrict__ sumsq,
                                    int* __restrict__ counts,
                                    int num_edges) {
    int e = blockIdx.x * blockDim.x + threadIdx.x;
    if (e >= num_edges) return;
    int d = dst[e];
    const float4* p = reinterpret_cast<const float4*>(scores + (size_t)e * NHEADS);
    float4 x0 = p[0], x1 = p[1];
    float* s = sums  + (size_t)d * NHEADS;
    float* q = sumsq + (size_t)d * NHEADS;
    atomicAdd(s + 0, x0.x); atomicAdd(s + 1, x0.y);
    atomicAdd(s + 2, x0.z); atomicAdd(s + 3, x0.w);
    atomicAdd(s + 4, x1.x); atomicAdd(s + 5, x1.y);
    atomicAdd(s + 6, x1.z); atomicAdd(s + 7, x1.w);
    atomicAdd(q + 0, x0.x * x0.x); atomicAdd(q + 1, x0.y * x0.y);
    atomicAdd(q + 2, x0.z * x0.z); atomicAdd(q + 3, x0.w * x0.w);
    atomicAdd(q + 4, x1.x * x1.x); atomicAdd(q + 5, x1.y * x1.y);
    atomicAdd(q + 6, x1.z * x1.z); atomicAdd(q + 7, x1.w * x1.w);
    atomicAdd(counts + d, 1);
}

__global__ void coeff_fallback(const float* __restrict__ sums,
                               const float* __restrict__ sumsq,
                               const int* __restrict__ counts,
                               const float* __restrict__ gain,
                               const float* __restrict__ bias,
                               float* __restrict__ AB, int total) {
    int i = blockIdx.x * blockDim.x + threadIdx.x;
    if (i >= total) return;
    int h = i & (NHEADS - 1);
    int node = i >> 3;
    float cm = fmaxf((float)counts[node], 1.0f);
    float s = sums[i];
    float mean = s / cm;
    float var_sum = fmaxf(sumsq[i] - s * mean, 0.0f);
    float inv = 1.0f / fmaxf(sqrtf(var_sum / cm), 1e-5f);
    float a = gain[h] * inv;
    AB[(size_t)node * 16 + h]     = a;
    AB[(size_t)node * 16 + 8 + h] = fmaf(-a, mean, bias[h]);
}
// ---------------------------------------------------------------------------

extern "C" void kernel_launch(void* const* d_in, const int* in_sizes, int n_in,
                              void* d_out, int out_size, void* d_ws, size_t ws_size,
                              hipStream_t stream) {
    const float* scores = (const float*)d_in[0];
    const float* gain   = (const float*)d_in[1];
    const float* bias   = (const float*)d_in[2];
    const int*   dst    = (const int*)d_in[3];

    const int E  = in_sizes[3];
    const int N  = NNODES;
    const int NH = N * NHEADS;
    const int B  = 256;

    // Fixed ws sections (256B-aligned):
    //   AB       : N*16 f32                        6.40 MB
    //   counts   : NB*CBLK u32                     0.40 MB
    //   totals   : NB u32        base : NB u32
    //   partials : NB*PARTS_B*KNODES*SLOTS f32    13.65 MB
    // Per-pass sections (P=4):
    //   payload  : passE*8 f32                    25.62 MB
    //   nidx     : passE u16                       1.60 MB
    // Total P=4 ~= 47.7 MB  (< 50.6 MB proven floor from round 4/5).
    size_t off = 0;
    float* AB = (float*)d_ws;                          off += (size_t)N * 16 * 4;
    off = (off + 255) & ~(size_t)255;
    unsigned* counts = (unsigned*)((char*)d_ws + off); off += (size_t)NB * CBLK * 4;
    off = (off + 255) & ~(size_t)255;
    unsigned* totals = (unsigned*)((char*)d_ws + off); off += (size_t)NB * 4;
    off = (off + 255) & ~(size_t)255;
    unsigned* baseb  = (unsigned*)((char*)d_ws + off); off += (size_t)NB * 4;
    off = (off + 255) & ~(size_t)255;
    float* partials  = (float*)((char*)d_ws + off);
    off += (size_t)NB * PARTS_B * KNODES * SLOTS * 4;
    off = (off + 255) & ~(size_t)255;
    const size_t fixed = off;

    // Choose pass count: smallest P with chunk<=CHMAX and ws fit.
    int P = 0, chunk = 0;
    size_t payOff = 0, nixOff = 0;
    size_t passCap = 0;
    const int cand[3] = {2, 4, 8};
    for (int ci = 0; ci < 3; ++ci) {
        int p = cand[ci];
        long long perPass = ((long long)E + p - 1) / p;
        long long ch = (((perPass + CBLK - 1) / CBLK) + 3) & ~3LL;
        if (ch > CHMAX) continue;
        size_t passE = (size_t)ch * CBLK;
        size_t po = fixed;
        size_t no = (po + passE * NHEADS * 4 + 255) & ~(size_t)255;
        size_t need = no + passE * 2;
        if (need <= ws_size) {
            P = p; chunk = (int)ch; payOff = po; nixOff = no; passCap = passE;
            break;
        }
    }

    if (P && E < (1 << 23)) {
        float* payload = (float*)((char*)d_ws + payOff);
        unsigned short* nidx = (unsigned short*)((char*)d_ws + nixOff);
        for (int pass = 0; pass < P; ++pass) {
            int p0 = pass * chunk * CBLK;
            if (p0 >= E) break;
            int p1 = min(E, p0 + chunk * CBLK);
            count_kernel<<<CBLK, B, 0, stream>>>(dst, counts, p0, p1, chunk);
            scan_kernel<<<NB, B, 0, stream>>>(counts, totals);
            base_kernel<<<1, B, 0, stream>>>(totals, baseb);
            scatter_kernel<<<CBLK, B, 0, stream>>>(dst, counts, baseb, scores,
                                                   payload, nidx, p0, p1, chunk,
                                                   (unsigned)passCap);
            dim3 gs(PARTS_B, NB);
            stats_kernel<<<gs, B, 0, stream>>>(payload, nidx, totals, baseb,
                                               partials, pass);
        }
        coeff_kernel<<<(NH + B - 1) / B, B, 0, stream>>>(partials, gain, bias, AB, NH);
        edge_out_kernel<<<(E + B - 1) / B, B, 0, stream>>>(scores, dst, AB,
                                                           (float*)d_out, E);
    } else {
        float* sums  = (float*)((char*)d_ws + (size_t)N * 16 * 4);
        float* sumsq = sums + NH;
        int*   cnts  = (int*)(sumsq + NH);
        hipMemsetAsync(sums, 0,
                       (size_t)(2 * NH) * sizeof(float) + (size_t)N * sizeof(int), stream);
        int blocks_e = (E + B - 1) / B;
        edge_stats_fallback<<<blocks_e, B, 0, stream>>>(scores, dst, sums, sumsq, cnts, E);
        coeff_fallback<<<(NH + B - 1) / B, B, 0, stream>>>(sums, sumsq, cnts, gain, bias, AB, NH);
        edge_out_kernel<<<blocks_e, B, 0, stream>>>(scores, dst, AB, (float*)d_out, E);
    }
}